// Round 13
// baseline (543.099 us; speedup 1.0000x reference)
//
#include <hip/hip_runtime.h>
#include <hip/hip_bf16.h>
#include <math.h>

#define PP 4096      // H*W
#define CCH 384      // channels
#define NB 16        // batch

using short8 = __attribute__((ext_vector_type(8))) short;
using f32x4  = __attribute__((ext_vector_type(4))) float;
using half2t = __attribute__((ext_vector_type(2))) __fp16;

__device__ __forceinline__ float sigmoidf_(float v){ return 1.f/(1.f+expf(-v)); }
__device__ __forceinline__ float fast_sig(float v){
  return __builtin_amdgcn_rcpf(1.f + __builtin_amdgcn_exp2f(-v*1.44269504088896f));
}
__device__ __forceinline__ unsigned int f2bf(float f){
  __hip_bfloat16 h = __float2bfloat16(f);
  return (unsigned int)*reinterpret_cast<unsigned short*>(&h);
}
__device__ __forceinline__ float bf2f(unsigned short u){
  unsigned int w = ((unsigned int)u) << 16;
  return __uint_as_float(w);
}
__device__ __forceinline__ void gload_lds16(const void* g, void* l){
  __builtin_amdgcn_global_load_lds(
      (const __attribute__((address_space(1))) unsigned int*)g,
      (__attribute__((address_space(3))) unsigned int*)l, 16, 0, 0);
}

// ---------------- prep ----------------
// grid 961: [0,576) WsumBf; [576,768) WcatBf; [768,864) g2wBf; [864,960) Wocat64 (x0.5); 960: A+t1/t2
__global__ __launch_bounds__(256) void k_prep(
    const float* __restrict__ rAl, const float* __restrict__ rU, const float* __restrict__ rV,
    const float* __restrict__ cAl, const float* __restrict__ cU, const float* __restrict__ cV,
    const float* __restrict__ rWs, const float* __restrict__ cWs,
    const float* __restrict__ WinR, const float* __restrict__ WgR,
    const float* __restrict__ WinC, const float* __restrict__ WgC,
    const float* __restrict__ g1w, const float* __restrict__ nw, const float* __restrict__ nb,
    const float* __restrict__ g2w,
    const float* __restrict__ WoR, const float* __restrict__ WoC,
    float* __restrict__ Arow, float* __restrict__ Acol,
    unsigned short* __restrict__ WsumBf, unsigned short* __restrict__ WcatBf,
    unsigned short* __restrict__ g2wBf, unsigned short* __restrict__ WocatBf,
    float* __restrict__ t1, float* __restrict__ t2)
{
  int bid = blockIdx.x, tid = threadIdx.x;
  if (bid < 576) {
    int idx = bid*256 + tid;
    WsumBf[idx] = (unsigned short)f2bf(rWs[idx] + cWs[idx]);
  } else if (bid < 768) {
    int idx = (bid-576)*256 + tid;
    int row = idx / CCH, col = idx - row*CCH;
    float v;
    if      (row < 16)  v = WinR[row*CCH + col];
    else if (row < 32)  v = WgR [(row-16)*CCH + col];
    else if (row < 48)  v = WinC[(row-32)*CCH + col];
    else if (row < 64)  v = WgC [(row-48)*CCH + col];
    else                v = g1w[(row-64)*CCH + col]*nw[col];
    WcatBf[idx] = (unsigned short)f2bf(v);
  } else if (bid < 864) {
    int idx = (bid-768)*256 + tid;
    g2wBf[idx] = (unsigned short)f2bf(g2w[idx]);
  } else if (bid < 960) {
    int idx = (bid-864)*256 + tid;   // [0, 24576): (c, k) k in 0..63
    int c = idx >> 6, k = idx & 63;
    int sel = (k >> 4) & 1;          // 0:WoR 1:WoC, duplicated for fwd/bwd halves
    float v = 0.5f * (sel ? WoC[c*16 + (k&15)] : WoR[c*16 + (k&15)]);
    WocatBf[idx] = (unsigned short)f2bf(v);
  } else {
    {
      int i = tid >> 4, j = tid & 15;
      float sr = 0.f, sc = 0.f;
      #pragma unroll
      for (int r=0;r<8;++r){ sr += rV[i*8+r]*rU[j*8+r]; sc += cV[i*8+r]*cU[j*8+r]; }
      if (i==j){ sr += sigmoidf_(rAl[i]); sc += sigmoidf_(cAl[i]); }
      Arow[tid] = sr; Acol[tid] = sc;
    }
    if (tid < 64) {
      float s1=0.f, s2=0.f;
      for (int c=0;c<CCH;++c){ s1 += g1w[tid*CCH+c]*nw[c]; s2 += nb[c]*g1w[tid*CCH+c]; }
      t1[tid]=s1; t2[tid]=s2;
    }
  }
}

// ---------------- xf: transpose + bf16 + stats + front MFMA GEMM (double-buffered tile) ----
__global__ __launch_bounds__(256) void k_xf(
    const float* __restrict__ x, const unsigned short* __restrict__ WcatBf,
    const float* __restrict__ binR, const float* __restrict__ bgR,
    const float* __restrict__ binC, const float* __restrict__ bgC,
    const float* __restrict__ t1, const float* __restrict__ t2,
    const float* __restrict__ g1b,
    unsigned short* __restrict__ xbf,
    float* __restrict__ ugr, float* __restrict__ ugc,
    unsigned short* __restrict__ h1bf)
{
  int b = blockIdx.x >> 6, pt = blockIdx.x & 63;
  int t = threadIdx.x;
  int w = t >> 6, l = t & 63;
  int lr = l & 15, kq = l >> 4, kb8 = kq*8;
  int pl = t & 63, g4 = w;

  __shared__ unsigned short xtb[2][64*64];   // 2 x 8KB double buffer
  __shared__ float red[512];
  __shared__ float meanS[64], invS[64];

  const float* xb = x + (size_t)b*CCH*PP + pt*64;
  f32x4 acc[2][4] = {};
  float sx = 0.f, sx2 = 0.f;

  const unsigned short* wrow0 = WcatBf + (size_t)(w*32 + lr)*CCH + kb8;
  const unsigned short* wrow1 = wrow0 + 16*CCH;
  unsigned short* xgo = xbf + ((size_t)(b*PP + pt*64))*CCH;

  float xv[16];
  #pragma unroll
  for (int j=0;j<16;++j) xv[j] = xb[(size_t)(g4*16 + j)*PP + pl];   // chunk 0

  // prologue: stats+pack chunk0 -> buf0
  {
    unsigned int pk[8];
    #pragma unroll
    for (int j=0;j<16;++j){ sx += xv[j]; sx2 += xv[j]*xv[j]; }
    #pragma unroll
    for (int j=0;j<8;++j) pk[j] = f2bf(xv[2*j]) | (f2bf(xv[2*j+1])<<16);
    int kg0 = g4*2, kg1 = g4*2+1;
    *(uint4*)&xtb[0][(size_t)(pl*8 + (kg0 ^ (pl&7)))*8] = make_uint4(pk[0],pk[1],pk[2],pk[3]);
    *(uint4*)&xtb[0][(size_t)(pl*8 + (kg1 ^ (pl&7)))*8] = make_uint4(pk[4],pk[5],pk[6],pk[7]);
  }
  #pragma unroll
  for (int j=0;j<16;++j) xv[j] = xb[(size_t)(64 + g4*16 + j)*PP + pl];  // chunk 1
  __syncthreads();   // buf0 visible

  #pragma unroll
  for (int cc=0; cc<6; ++cc) {
    int cur = cc & 1;
    if (cc < 5) {
      unsigned int pk[8];
      #pragma unroll
      for (int j=0;j<16;++j){ sx += xv[j]; sx2 += xv[j]*xv[j]; }
      #pragma unroll
      for (int j=0;j<8;++j) pk[j] = f2bf(xv[2*j]) | (f2bf(xv[2*j+1])<<16);
      int kg0 = g4*2, kg1 = g4*2+1;
      *(uint4*)&xtb[cur^1][(size_t)(pl*8 + (kg0 ^ (pl&7)))*8] = make_uint4(pk[0],pk[1],pk[2],pk[3]);
      *(uint4*)&xtb[cur^1][(size_t)(pl*8 + (kg1 ^ (pl&7)))*8] = make_uint4(pk[4],pk[5],pk[6],pk[7]);
      if (cc < 4) {
        #pragma unroll
        for (int j=0;j<16;++j) xv[j] = xb[(size_t)((cc+2)*64 + g4*16 + j)*PP + pl];
      }
    }
    short8 a0k0 = *(const short8*)(wrow0 + cc*64);
    short8 a0k1 = *(const short8*)(wrow0 + cc*64 + 32);
    short8 a1k0 = *(const short8*)(wrow1 + cc*64);
    short8 a1k1 = *(const short8*)(wrow1 + cc*64 + 32);
    #pragma unroll
    for (int ks=0; ks<2; ++ks){
      int kg = ks*4 + kq;
      #pragma unroll
      for (int nf=0; nf<4; ++nf){
        int pr = nf*16 + lr;
        short8 bv = *(const short8*)&xtb[cur][(size_t)(pr*8 + (kg ^ (pr&7)))*8];
        acc[0][nf] = __builtin_amdgcn_mfma_f32_16x16x32_bf16(ks? a0k1:a0k0, bv, acc[0][nf], 0,0,0);
        acc[1][nf] = __builtin_amdgcn_mfma_f32_16x16x32_bf16(ks? a1k1:a1k0, bv, acc[1][nf], 0,0,0);
      }
    }
    #pragma unroll
    for (int it=0; it<2; ++it){
      int p2 = 32*it + (t>>3), kg2 = t & 7;
      uint4 v = *(const uint4*)&xtb[cur][(size_t)(p2*8 + (kg2 ^ (p2&7)))*8];
      *(uint4*)&xgo[(size_t)p2*CCH + cc*64 + kg2*8] = v;
    }
    __syncthreads();
  }

  red[g4*64 + pl] = sx;
  red[256 + g4*64 + pl] = sx2;
  __syncthreads();
  if (t < 64) {
    float s1 = red[t] + red[64+t] + red[128+t] + red[192+t];
    float s2 = red[256+t] + red[320+t] + red[384+t] + red[448+t];
    float mu = s1 * (1.f/CCH);
    float var = s2 * (1.f/CCH) - mu*mu;
    meanS[t] = mu;
    invS[t]  = rsqrtf(var + 1e-6f);
  }
  __syncthreads();

  if (w < 2) {
    const float* bu = w ? binC : binR;
    const float* bg = w ? bgC  : bgR;
    float* dst = w ? ugc : ugr;
    float bus[4], bgs[4];
    #pragma unroll
    for (int r=0;r<4;++r){ int s = kq*4 + r; bus[r]=bu[s]; bgs[r]=bg[s]; }
    #pragma unroll
    for (int nf=0; nf<4; ++nf){
      size_t pbase = ((size_t)(b*PP + pt*64 + nf*16 + lr))*16;
      #pragma unroll
      for (int r=0;r<4;++r){
        int s = kq*4 + r;
        float u = acc[0][nf][r] + bus[r];
        float g = fast_sig(acc[1][nf][r] + bgs[r]);
        dst[pbase + s] = u*g;
      }
    }
  } else {
    int ob = (w-2)*32 + kq*4;
    float t1o[2][4], t2o[2][4], gbo[2][4];
    #pragma unroll
    for (int mi=0;mi<2;++mi)
      #pragma unroll
      for (int r=0;r<4;++r){
        int o = ob + mi*16 + r;
        t1o[mi][r]=t1[o]; t2o[mi][r]=t2[o]; gbo[mi][r]=g1b[o];
      }
    #pragma unroll
    for (int nf=0; nf<4; ++nf){
      int pLoc = nf*16 + lr;
      float mu = meanS[pLoc], iv = invS[pLoc];
      #pragma unroll
      for (int mi=0;mi<2;++mi){
        unsigned int us[4];
        #pragma unroll
        for (int r=0;r<4;++r){
          float pre = iv*(acc[mi][nf][r] - mu*t1o[mi][r]) + t2o[mi][r] + gbo[mi][r];
          float aa = pre*(1.f + 0.044715f*pre*pre);
          float ge = pre*fast_sig(1.5957691216f*aa);
          us[r] = f2bf(ge);
        }
        uint2 o2; o2.x = us[0] | (us[1]<<16); o2.y = us[2] | (us[3]<<16);
        *reinterpret_cast<uint2*>(h1bf + ((size_t)(b*PP + pt*64 + pLoc))*64 + (w-2)*32 + mi*16 + kq*4) = o2;
      }
    }
  }
}

// ---------------- scan: 4096 tasks, 2 per wave (32 lanes each); gu prefetch ----------------
__global__ __launch_bounds__(256) void k_scan(
    const float* __restrict__ ugr, const float* __restrict__ ugc,
    const float* __restrict__ Arow, const float* __restrict__ Acol,
    unsigned short* __restrict__ hs2)
{
  int Wv = blockIdx.x*4 + (threadIdx.x >> 6);
  int lane = threadIdx.x & 63;
  int tsk = Wv*2 + (lane >> 5);
  int base32 = lane & 32;
  int half = (lane >> 4) & 1, s = lane & 15;
  int dir = tsk >> 11;
  int rem = tsk & 2047;
  int isCol = rem >> 10;
  int gg = rem & 1023;
  int b = gg >> 6, rc = gg & 63;
  const float* ug = isCol ? ugc : ugr;
  const float* A  = isCol ? Acol : Arow;
  int off = dir*32 + isCol*16;
  int p0 = b*PP + (isCol ? rc : rc*64);
  int stride = isCol ? 64 : 1;
  float ac[8];
  #pragma unroll
  for (int i=0;i<8;++i) ac[i] = A[(half*8 + i)*16 + s];
  float h = 0.f;
  int l2_0 = dir ? 63 : 0;
  float gu = ug[((size_t)(p0 + l2_0*stride))*16 + s];
  #pragma unroll 4
  for (int st=0; st<64; ++st){
    int l2 = dir ? (63-st) : st;
    float gu_next = 0.f;
    if (st < 63){
      int l2n = dir ? (62-st) : (st+1);
      gu_next = ug[((size_t)(p0 + l2n*stride))*16 + s];
    }
    float part = 0.f;
    #pragma unroll
    for (int i=0;i<8;++i) part += __shfl(h, base32 + half*8 + i, 64) * ac[i];
    float tt = part + __shfl_xor(part, 16, 64);
    h = tt + gu;
    if (!(lane & 16))
      hs2[((size_t)(p0 + l2*stride))*64 + off + s] = (unsigned short)f2bf(h);
    gu = gu_next;
  }
}

// ---------------- fused: 384c x 64p; K split in 2 halves over ONE 24KB buffer ----------
// grid 1024 = (b, pt) XCD-swizzled; 8 waves (512 thr); wave w: c-rows w*48 + mi*16
// 24KB LDS + 64 VGPR target -> 4 blocks/CU resident (vs 2 at 48KB)
__global__ __launch_bounds__(512, 8) void k_fused(
    const unsigned short* __restrict__ xbf,
    const unsigned short* __restrict__ WsumBf,
    const unsigned short* __restrict__ h1bf, const unsigned short* __restrict__ g2wBf,
    const unsigned short* __restrict__ hs2, const unsigned short* __restrict__ WocatBf,
    const float* __restrict__ g2b,
    const float* __restrict__ boR, const float* __restrict__ bsR,
    const float* __restrict__ boC, const float* __restrict__ bsC,
    float* __restrict__ outp)
{
  int obid = blockIdx.x;
  int bid = ((obid & 7) * 128) + (obid >> 3);   // 1024 = 8*128 bijective
  int b = bid >> 6, pt = bid & 63;
  int t = threadIdx.x;
  int w = t >> 6, l = t & 63;
  int lr = l & 15, kq = l >> 4, kb8 = kq * 8;
  int cw = w*48;

  __shared__ unsigned short xt[64*24*8];    // 24KB: granule (p,kgs) at p*24+kgs; one K-half

  const unsigned short* xrow0 = xbf + ((size_t)(b*PP + pt*64))*CCH;

  // ---- gate operand loads ----
  short8 gaw[3][2], gbv[2][4];
  {
    const unsigned short* hbase = h1bf + ((size_t)(b*PP + pt*64 + lr))*64 + kb8;
    #pragma unroll
    for (int ks=0; ks<2; ++ks)
      #pragma unroll
      for (int nf=0; nf<4; ++nf)
        gbv[ks][nf] = *(const short8*)(hbase + (size_t)nf*16*64 + ks*32);
    #pragma unroll
    for (int mi=0; mi<3; ++mi){
      const unsigned short* wbg = g2wBf + (size_t)(cw + mi*16 + lr)*64 + kb8;
      gaw[mi][0] = *(const short8*)(wbg);
      gaw[mi][1] = *(const short8*)(wbg + 32);
    }
  }

  // ---- stage half0 (c 0..191): 1536 granules, 3 issues/thread ----
  #pragma unroll
  for (int i=0;i<3;++i){
    int G = w*192 + i*64 + l;
    int p = G/24, kgs = G - p*24;
    int kg = (kgs & ~7) | ((kgs & 7) ^ (p & 7));
    gload_lds16(xrow0 + (size_t)p*CCH + kg*8, &xt[(size_t)G*8]);
  }

  // ---- gate MFMAs + fast sigmoid + f16 pack (under stage-0 flight) ----
  unsigned int gt[3][4][2];
  {
    f32x4 gac[3][4] = {};
    #pragma unroll
    for (int ks=0; ks<2; ++ks)
      #pragma unroll
      for (int nf=0; nf<4; ++nf)
        #pragma unroll
        for (int mi=0; mi<3; ++mi)
          gac[mi][nf] = __builtin_amdgcn_mfma_f32_16x16x32_bf16(gaw[mi][ks], gbv[ks][nf], gac[mi][nf], 0,0,0);
    #pragma unroll
    for (int mi=0;mi<3;++mi){
      float4 gb4 = *(const float4*)&g2b[cw + mi*16 + kq*4];
      #pragma unroll
      for (int nf=0;nf<4;++nf){
        float s0 = fast_sig(gac[mi][nf][0] + gb4.x);
        float s1 = fast_sig(gac[mi][nf][1] + gb4.y);
        float s2 = fast_sig(gac[mi][nf][2] + gb4.z);
        float s3 = fast_sig(gac[mi][nf][3] + gb4.w);
        half2t p01 = __builtin_amdgcn_cvt_pkrtz(s0, s1);
        half2t p23 = __builtin_amdgcn_cvt_pkrtz(s2, s3);
        __builtin_memcpy(&gt[mi][nf][0], &p01, 4);
        __builtin_memcpy(&gt[mi][nf][1], &p23, 4);
      }
    }
  }

  __syncthreads();   // half0 resident

  f32x4 acc[3][4] = {};
  const unsigned short* wbS = WsumBf + (size_t)(cw + lr)*CCH + kb8;
  uint2 xres[4];
  int cb0q = cw + kq*4;              // this thread's first c-row (mi=0)

  // ---- K loop half0: global chunks 0..2 ----
  #pragma unroll
  for (int c=0;c<3;++c){
    short8 a[3][2];
    #pragma unroll
    for (int mi=0;mi<3;++mi){
      a[mi][0] = *(const short8*)(wbS + (size_t)mi*16*CCH + c*64);
      a[mi][1] = *(const short8*)(wbS + (size_t)mi*16*CCH + c*64 + 32);
    }
    #pragma unroll
    for (int ks=0;ks<2;++ks){
      int kgl = ks*4 + kq;
      #pragma unroll
      for (int nf=0;nf<4;++nf){
        int pr = nf*16 + lr;
        int kgs = c*8 + (kgl ^ (pr & 7));
        short8 bv = *(const short8*)&xt[(size_t)(pr*24 + kgs)*8];
        #pragma unroll
        for (int mi=0;mi<3;++mi)
          acc[mi][nf] = __builtin_amdgcn_mfma_f32_16x16x32_bf16(a[mi][ks], bv, acc[mi][nf], 0,0,0);
      }
    }
  }
  // residual rows for waves 0..3 live in half0 (c < 192): extract all 3 mi now into
  // a compact per-thread cache held in gt-style registers via re-read later -> store to xres via loop
  uint2 xresAll[3][4];
  if (w < 4) {
    #pragma unroll
    for (int mi=0;mi<3;++mi){
      int cb0 = cb0q + mi*16;
      int kgR = cb0 >> 3, eoff = cb0 & 7;
      #pragma unroll
      for (int nf=0;nf<4;++nf){
        int p = nf*16 + lr;
        int kgsR = (kgR & ~7) | ((kgR & 7) ^ (p & 7));
        xresAll[mi][nf] = *(const uint2*)&xt[(size_t)(p*24 + kgsR)*8 + eoff];
      }
    }
  }
  (void)xres;

  __syncthreads();   // all half0 reads done -> safe to overwrite

  // ---- stage half1 (c 192..383) ----
  #pragma unroll
  for (int i=0;i<3;++i){
    int G = w*192 + i*64 + l;
    int p = G/24, kgs = G - p*24;
    int kg = (kgs & ~7) | ((kgs & 7) ^ (p & 7));
    gload_lds16(xrow0 + (size_t)p*CCH + 192 + kg*8, &xt[(size_t)G*8]);
  }

  __syncthreads();   // half1 resident

  // ---- K loop half1: global chunks 3..5 (local 0..2) ----
  #pragma unroll
  for (int c=0;c<3;++c){
    short8 a[3][2];
    #pragma unroll
    for (int mi=0;mi<3;++mi){
      a[mi][0] = *(const short8*)(wbS + (size_t)mi*16*CCH + (c+3)*64);
      a[mi][1] = *(const short8*)(wbS + (size_t)mi*16*CCH + (c+3)*64 + 32);
    }
    #pragma unroll
    for (int ks=0;ks<2;++ks){
      int kgl = ks*4 + kq;
      #pragma unroll
      for (int nf=0;nf<4;++nf){
        int pr = nf*16 + lr;
        int kgs = c*8 + (kgl ^ (pr & 7));
        short8 bv = *(const short8*)&xt[(size_t)(pr*24 + kgs)*8];
        #pragma unroll
        for (int mi=0;mi<3;++mi)
          acc[mi][nf] = __builtin_amdgcn_mfma_f32_16x16x32_bf16(a[mi][ks], bv, acc[mi][nf], 0,0,0);
      }
    }
  }
  // residual rows for waves 4..7 live in half1
  if (w >= 4) {
    #pragma unroll
    for (int mi=0;mi<3;++mi){
      int cb0 = cb0q + mi*16 - 192;
      int kgR = cb0 >> 3, eoff = cb0 & 7;
      #pragma unroll
      for (int nf=0;nf<4;++nf){
        int p = nf*16 + lr;
        int kgsR = (kgR & ~7) | ((kgR & 7) ^ (p & 7));
        xresAll[mi][nf] = *(const uint2*)&xt[(size_t)(p*24 + kgsR)*8 + eoff];
      }
    }
  }

  // ---- phase C: K=64 over [hfR|hfC|hbR|hbC] with 0.5-scaled Wocat, into acc ----
  {
    const unsigned short* hb2 = hs2 + ((size_t)(b*PP + pt*64 + lr))*64 + kb8;
    short8 hv[2][4];
    #pragma unroll
    for (int ks=0;ks<2;++ks)
      #pragma unroll
      for (int nf=0;nf<4;++nf)
        hv[ks][nf] = *(const short8*)(hb2 + (size_t)nf*16*64 + ks*32);
    #pragma unroll
    for (int mi=0;mi<3;++mi){
      const unsigned short* wo = WocatBf + (size_t)(cw + mi*16 + lr)*64 + kb8;
      short8 wa0 = *(const short8*)(wo);
      short8 wa1 = *(const short8*)(wo + 32);
      #pragma unroll
      for (int nf=0;nf<4;++nf){
        acc[mi][nf] = __builtin_amdgcn_mfma_f32_16x16x32_bf16(wa0, hv[0][nf], acc[mi][nf], 0,0,0);
        acc[mi][nf] = __builtin_amdgcn_mfma_f32_16x16x32_bf16(wa1, hv[1][nf], acc[mi][nf], 0,0,0);
      }
    }
  }

  // ---- epilogue: y = 0.5*acc + 0.5*(bias sums); residual from xresAll; gt unpack ----
  #pragma unroll
  for (int mi=0;mi<3;++mi){
    int cb0 = cw + mi*16 + kq*4;
    float4 b1 = *(const float4*)&boR[cb0];
    float4 b2 = *(const float4*)&bsR[cb0];
    float4 b3 = *(const float4*)&boC[cb0];
    float4 b4 = *(const float4*)&bsC[cb0];
    float cb4[4] = { b1.x+b2.x+b3.x+b4.x, b1.y+b2.y+b3.y+b4.y,
                     b1.z+b2.z+b3.z+b4.z, b1.w+b2.w+b3.w+b4.w };
    #pragma unroll
    for (int nf=0;nf<4;++nf){
      int p = nf*16 + lr;
      uint2 xr = xresAll[mi][nf];
      half2t g01, g23;
      __builtin_memcpy(&g01, &gt[mi][nf][0], 4);
      __builtin_memcpy(&g23, &gt[mi][nf][1], 4);
      float gv[4] = { (float)g01[0], (float)g01[1], (float)g23[0], (float)g23[1] };
      #pragma unroll
      for (int r=0;r<4;++r){
        unsigned int word = (r < 2) ? xr.x : xr.y;
        unsigned short us = (r & 1) ? (unsigned short)(word >> 16) : (unsigned short)(word & 0xffff);
        float xv = bf2f(us);
        float y = 0.5f*acc[mi][nf][r] + 0.5f*cb4[r];
        float gtv = gv[r];
        size_t addr = ((size_t)(b*CCH + cb0 + r))*PP + pt*64 + p;
        outp[addr] = gtv*y + (1.f-gtv)*xv;
      }
    }
  }
}

extern "C" void kernel_launch(void* const* d_in, const int* in_sizes, int n_in,
                              void* d_out, int out_size, void* d_ws, size_t ws_size,
                              hipStream_t stream)
{
  const float* x    = (const float*)d_in[0];
  const float* rAl  = (const float*)d_in[1];
  const float* rU   = (const float*)d_in[2];
  const float* rV   = (const float*)d_in[3];
  const float* rWin = (const float*)d_in[4];
  const float* rbin = (const float*)d_in[5];
  const float* rWg  = (const float*)d_in[6];
  const float* rbg  = (const float*)d_in[7];
  const float* rWo  = (const float*)d_in[8];
  const float* rbo  = (const float*)d_in[9];
  const float* rWs  = (const float*)d_in[10];
  const float* rbs  = (const float*)d_in[11];
  const float* cAl  = (const float*)d_in[12];
  const float* cU   = (const float*)d_in[13];
  const float* cV   = (const float*)d_in[14];
  const float* cWin = (const float*)d_in[15];
  const float* cbin = (const float*)d_in[16];
  const float* cWg  = (const float*)d_in[17];
  const float* cbg  = (const float*)d_in[18];
  const float* cWo  = (const float*)d_in[19];
  const float* cbo  = (const float*)d_in[20];
  const float* cWs  = (const float*)d_in[21];
  const float* cbs  = (const float*)d_in[22];
  const float* g1w  = (const float*)d_in[23];
  const float* g1b  = (const float*)d_in[24];
  const float* g2w  = (const float*)d_in[25];
  const float* g2b  = (const float*)d_in[26];
  const float* nw   = (const float*)d_in[27];
  const float* nb   = (const float*)d_in[28];

  float* ws   = (float*)d_ws;
  float* ugr  = ws;                    // 1048576 (B,P,16) fp32
  float* ugc  = ugr + 1048576;         // 1048576
  float* Arow = ugc + 1048576;         // 256
  float* Acol = Arow + 256;            // 256
  float* t1   = Acol + 256;            // 64
  float* t2   = t1 + 64;               // 64
  unsigned short* xbf     = (unsigned short*)(t2 + 64);   // 16*4096*384 = 25165824
  unsigned short* h1bf    = xbf + (size_t)25165824;       // 16*4096*64  = 4194304
  unsigned short* hs2     = h1bf + (size_t)4194304;       // 16*4096*64  = 4194304
  unsigned short* WsumBf  = hs2 + (size_t)4194304;        // 147456
  unsigned short* WcatBf  = WsumBf + 147456;              // 49152
  unsigned short* g2wBf   = WcatBf + 49152;               // 24576
  unsigned short* WocatBf = g2wBf + 24576;                // 24576
  float* outp = (float*)d_out;

  k_prep<<<961, 256, 0, stream>>>(rAl,rU,rV,cAl,cU,cV,rWs,cWs,
                                  rWin,rWg,cWin,cWg,g1w,nw,nb,g2w,rWo,cWo,
                                  Arow,Acol,WsumBf,WcatBf,g2wBf,WocatBf,t1,t2);
  k_xf<<<1024, 256, 0, stream>>>(x, WcatBf, rbin, rbg, cbin, cbg,
                                 t1, t2, g1b, xbf, ugr, ugc, h1bf);
  k_scan<<<512, 256, 0, stream>>>(ugr, ugc, Arow, Acol, hs2);
  k_fused<<<1024, 512, 0, stream>>>(xbf, WsumBf, h1bf, g2wBf,
                                    hs2, WocatBf, g2b,
                                    rbo, rbs, cbo, cbs, outp);
}

// Round 14
// 221.850 us; speedup vs baseline: 2.4480x; 2.4480x over previous
//
#include <hip/hip_runtime.h>
#include <hip/hip_bf16.h>
#include <math.h>

#define PP 4096      // H*W
#define CCH 384      // channels
#define NB 16        // batch

using short8 = __attribute__((ext_vector_type(8))) short;
using f32x4  = __attribute__((ext_vector_type(4))) float;
using half2t = __attribute__((ext_vector_type(2))) __fp16;

__device__ __forceinline__ float sigmoidf_(float v){ return 1.f/(1.f+expf(-v)); }
__device__ __forceinline__ float fast_sig(float v){
  return __builtin_amdgcn_rcpf(1.f + __builtin_amdgcn_exp2f(-v*1.44269504088896f));
}
__device__ __forceinline__ unsigned int f2bf(float f){
  __hip_bfloat16 h = __float2bfloat16(f);
  return (unsigned int)*reinterpret_cast<unsigned short*>(&h);
}
__device__ __forceinline__ float bf2f(unsigned short u){
  unsigned int w = ((unsigned int)u) << 16;
  return __uint_as_float(w);
}
__device__ __forceinline__ void gload_lds16(const void* g, void* l){
  __builtin_amdgcn_global_load_lds(
      (const __attribute__((address_space(1))) unsigned int*)g,
      (__attribute__((address_space(3))) unsigned int*)l, 16, 0, 0);
}

// ---------------- prep ----------------
// grid 961: [0,576) WsumBf; [576,768) WcatBf; [768,864) g2wBf; [864,960) Wocat64 (x0.5); 960: A+t1/t2
__global__ __launch_bounds__(256) void k_prep(
    const float* __restrict__ rAl, const float* __restrict__ rU, const float* __restrict__ rV,
    const float* __restrict__ cAl, const float* __restrict__ cU, const float* __restrict__ cV,
    const float* __restrict__ rWs, const float* __restrict__ cWs,
    const float* __restrict__ WinR, const float* __restrict__ WgR,
    const float* __restrict__ WinC, const float* __restrict__ WgC,
    const float* __restrict__ g1w, const float* __restrict__ nw, const float* __restrict__ nb,
    const float* __restrict__ g2w,
    const float* __restrict__ WoR, const float* __restrict__ WoC,
    float* __restrict__ Arow, float* __restrict__ Acol,
    unsigned short* __restrict__ WsumBf, unsigned short* __restrict__ WcatBf,
    unsigned short* __restrict__ g2wBf, unsigned short* __restrict__ WocatBf,
    float* __restrict__ t1, float* __restrict__ t2)
{
  int bid = blockIdx.x, tid = threadIdx.x;
  if (bid < 576) {
    int idx = bid*256 + tid;
    WsumBf[idx] = (unsigned short)f2bf(rWs[idx] + cWs[idx]);
  } else if (bid < 768) {
    int idx = (bid-576)*256 + tid;
    int row = idx / CCH, col = idx - row*CCH;
    float v;
    if      (row < 16)  v = WinR[row*CCH + col];
    else if (row < 32)  v = WgR [(row-16)*CCH + col];
    else if (row < 48)  v = WinC[(row-32)*CCH + col];
    else if (row < 64)  v = WgC [(row-48)*CCH + col];
    else                v = g1w[(row-64)*CCH + col]*nw[col];
    WcatBf[idx] = (unsigned short)f2bf(v);
  } else if (bid < 864) {
    int idx = (bid-768)*256 + tid;
    g2wBf[idx] = (unsigned short)f2bf(g2w[idx]);
  } else if (bid < 960) {
    int idx = (bid-864)*256 + tid;   // [0, 24576): (c, k) k in 0..63
    int c = idx >> 6, k = idx & 63;
    int sel = (k >> 4) & 1;          // 0:WoR 1:WoC, duplicated for fwd/bwd halves
    float v = 0.5f * (sel ? WoC[c*16 + (k&15)] : WoR[c*16 + (k&15)]);
    WocatBf[idx] = (unsigned short)f2bf(v);
  } else {
    {
      int i = tid >> 4, j = tid & 15;
      float sr = 0.f, sc = 0.f;
      #pragma unroll
      for (int r=0;r<8;++r){ sr += rV[i*8+r]*rU[j*8+r]; sc += cV[i*8+r]*cU[j*8+r]; }
      if (i==j){ sr += sigmoidf_(rAl[i]); sc += sigmoidf_(cAl[i]); }
      Arow[tid] = sr; Acol[tid] = sc;
    }
    if (tid < 64) {
      float s1=0.f, s2=0.f;
      for (int c=0;c<CCH;++c){ s1 += g1w[tid*CCH+c]*nw[c]; s2 += nb[c]*g1w[tid*CCH+c]; }
      t1[tid]=s1; t2[tid]=s2;
    }
  }
}

// ---------------- xf: transpose + bf16 + stats + front MFMA GEMM (double-buffered tile) ----
__global__ __launch_bounds__(256) void k_xf(
    const float* __restrict__ x, const unsigned short* __restrict__ WcatBf,
    const float* __restrict__ binR, const float* __restrict__ bgR,
    const float* __restrict__ binC, const float* __restrict__ bgC,
    const float* __restrict__ t1, const float* __restrict__ t2,
    const float* __restrict__ g1b,
    unsigned short* __restrict__ xbf,
    float* __restrict__ ugr, float* __restrict__ ugc,
    unsigned short* __restrict__ h1bf)
{
  int b = blockIdx.x >> 6, pt = blockIdx.x & 63;
  int t = threadIdx.x;
  int w = t >> 6, l = t & 63;
  int lr = l & 15, kq = l >> 4, kb8 = kq*8;
  int pl = t & 63, g4 = w;

  __shared__ unsigned short xtb[2][64*64];   // 2 x 8KB double buffer
  __shared__ float red[512];
  __shared__ float meanS[64], invS[64];

  const float* xb = x + (size_t)b*CCH*PP + pt*64;
  f32x4 acc[2][4] = {};
  float sx = 0.f, sx2 = 0.f;

  const unsigned short* wrow0 = WcatBf + (size_t)(w*32 + lr)*CCH + kb8;
  const unsigned short* wrow1 = wrow0 + 16*CCH;
  unsigned short* xgo = xbf + ((size_t)(b*PP + pt*64))*CCH;

  float xv[16];
  #pragma unroll
  for (int j=0;j<16;++j) xv[j] = xb[(size_t)(g4*16 + j)*PP + pl];   // chunk 0

  // prologue: stats+pack chunk0 -> buf0
  {
    unsigned int pk[8];
    #pragma unroll
    for (int j=0;j<16;++j){ sx += xv[j]; sx2 += xv[j]*xv[j]; }
    #pragma unroll
    for (int j=0;j<8;++j) pk[j] = f2bf(xv[2*j]) | (f2bf(xv[2*j+1])<<16);
    int kg0 = g4*2, kg1 = g4*2+1;
    *(uint4*)&xtb[0][(size_t)(pl*8 + (kg0 ^ (pl&7)))*8] = make_uint4(pk[0],pk[1],pk[2],pk[3]);
    *(uint4*)&xtb[0][(size_t)(pl*8 + (kg1 ^ (pl&7)))*8] = make_uint4(pk[4],pk[5],pk[6],pk[7]);
  }
  #pragma unroll
  for (int j=0;j<16;++j) xv[j] = xb[(size_t)(64 + g4*16 + j)*PP + pl];  // chunk 1
  __syncthreads();   // buf0 visible

  #pragma unroll
  for (int cc=0; cc<6; ++cc) {
    int cur = cc & 1;
    if (cc < 5) {
      unsigned int pk[8];
      #pragma unroll
      for (int j=0;j<16;++j){ sx += xv[j]; sx2 += xv[j]*xv[j]; }
      #pragma unroll
      for (int j=0;j<8;++j) pk[j] = f2bf(xv[2*j]) | (f2bf(xv[2*j+1])<<16);
      int kg0 = g4*2, kg1 = g4*2+1;
      *(uint4*)&xtb[cur^1][(size_t)(pl*8 + (kg0 ^ (pl&7)))*8] = make_uint4(pk[0],pk[1],pk[2],pk[3]);
      *(uint4*)&xtb[cur^1][(size_t)(pl*8 + (kg1 ^ (pl&7)))*8] = make_uint4(pk[4],pk[5],pk[6],pk[7]);
      if (cc < 4) {
        #pragma unroll
        for (int j=0;j<16;++j) xv[j] = xb[(size_t)((cc+2)*64 + g4*16 + j)*PP + pl];
      }
    }
    short8 a0k0 = *(const short8*)(wrow0 + cc*64);
    short8 a0k1 = *(const short8*)(wrow0 + cc*64 + 32);
    short8 a1k0 = *(const short8*)(wrow1 + cc*64);
    short8 a1k1 = *(const short8*)(wrow1 + cc*64 + 32);
    #pragma unroll
    for (int ks=0; ks<2; ++ks){
      int kg = ks*4 + kq;
      #pragma unroll
      for (int nf=0; nf<4; ++nf){
        int pr = nf*16 + lr;
        short8 bv = *(const short8*)&xtb[cur][(size_t)(pr*8 + (kg ^ (pr&7)))*8];
        acc[0][nf] = __builtin_amdgcn_mfma_f32_16x16x32_bf16(ks? a0k1:a0k0, bv, acc[0][nf], 0,0,0);
        acc[1][nf] = __builtin_amdgcn_mfma_f32_16x16x32_bf16(ks? a1k1:a1k0, bv, acc[1][nf], 0,0,0);
      }
    }
    #pragma unroll
    for (int it=0; it<2; ++it){
      int p2 = 32*it + (t>>3), kg2 = t & 7;
      uint4 v = *(const uint4*)&xtb[cur][(size_t)(p2*8 + (kg2 ^ (p2&7)))*8];
      *(uint4*)&xgo[(size_t)p2*CCH + cc*64 + kg2*8] = v;
    }
    __syncthreads();
  }

  red[g4*64 + pl] = sx;
  red[256 + g4*64 + pl] = sx2;
  __syncthreads();
  if (t < 64) {
    float s1 = red[t] + red[64+t] + red[128+t] + red[192+t];
    float s2 = red[256+t] + red[320+t] + red[384+t] + red[448+t];
    float mu = s1 * (1.f/CCH);
    float var = s2 * (1.f/CCH) - mu*mu;
    meanS[t] = mu;
    invS[t]  = rsqrtf(var + 1e-6f);
  }
  __syncthreads();

  if (w < 2) {
    const float* bu = w ? binC : binR;
    const float* bg = w ? bgC  : bgR;
    float* dst = w ? ugc : ugr;
    float bus[4], bgs[4];
    #pragma unroll
    for (int r=0;r<4;++r){ int s = kq*4 + r; bus[r]=bu[s]; bgs[r]=bg[s]; }
    #pragma unroll
    for (int nf=0; nf<4; ++nf){
      size_t pbase = ((size_t)(b*PP + pt*64 + nf*16 + lr))*16;
      #pragma unroll
      for (int r=0;r<4;++r){
        int s = kq*4 + r;
        float u = acc[0][nf][r] + bus[r];
        float g = fast_sig(acc[1][nf][r] + bgs[r]);
        dst[pbase + s] = u*g;
      }
    }
  } else {
    int ob = (w-2)*32 + kq*4;
    float t1o[2][4], t2o[2][4], gbo[2][4];
    #pragma unroll
    for (int mi=0;mi<2;++mi)
      #pragma unroll
      for (int r=0;r<4;++r){
        int o = ob + mi*16 + r;
        t1o[mi][r]=t1[o]; t2o[mi][r]=t2[o]; gbo[mi][r]=g1b[o];
      }
    #pragma unroll
    for (int nf=0; nf<4; ++nf){
      int pLoc = nf*16 + lr;
      float mu = meanS[pLoc], iv = invS[pLoc];
      #pragma unroll
      for (int mi=0;mi<2;++mi){
        unsigned int us[4];
        #pragma unroll
        for (int r=0;r<4;++r){
          float pre = iv*(acc[mi][nf][r] - mu*t1o[mi][r]) + t2o[mi][r] + gbo[mi][r];
          float aa = pre*(1.f + 0.044715f*pre*pre);
          float ge = pre*fast_sig(1.5957691216f*aa);
          us[r] = f2bf(ge);
        }
        uint2 o2; o2.x = us[0] | (us[1]<<16); o2.y = us[2] | (us[3]<<16);
        *reinterpret_cast<uint2*>(h1bf + ((size_t)(b*PP + pt*64 + pLoc))*64 + (w-2)*32 + mi*16 + kq*4) = o2;
      }
    }
  }
}

// ---------------- scan: 4096 tasks, 2 per wave (32 lanes each); gu prefetch ----------------
__global__ __launch_bounds__(256) void k_scan(
    const float* __restrict__ ugr, const float* __restrict__ ugc,
    const float* __restrict__ Arow, const float* __restrict__ Acol,
    unsigned short* __restrict__ hs2)
{
  int Wv = blockIdx.x*4 + (threadIdx.x >> 6);
  int lane = threadIdx.x & 63;
  int tsk = Wv*2 + (lane >> 5);
  int base32 = lane & 32;
  int half = (lane >> 4) & 1, s = lane & 15;
  int dir = tsk >> 11;
  int rem = tsk & 2047;
  int isCol = rem >> 10;
  int gg = rem & 1023;
  int b = gg >> 6, rc = gg & 63;
  const float* ug = isCol ? ugc : ugr;
  const float* A  = isCol ? Acol : Arow;
  int off = dir*32 + isCol*16;
  int p0 = b*PP + (isCol ? rc : rc*64);
  int stride = isCol ? 64 : 1;
  float ac[8];
  #pragma unroll
  for (int i=0;i<8;++i) ac[i] = A[(half*8 + i)*16 + s];
  float h = 0.f;
  int l2_0 = dir ? 63 : 0;
  float gu = ug[((size_t)(p0 + l2_0*stride))*16 + s];
  #pragma unroll 4
  for (int st=0; st<64; ++st){
    int l2 = dir ? (63-st) : st;
    float gu_next = 0.f;
    if (st < 63){
      int l2n = dir ? (62-st) : (st+1);
      gu_next = ug[((size_t)(p0 + l2n*stride))*16 + s];
    }
    float part = 0.f;
    #pragma unroll
    for (int i=0;i<8;++i) part += __shfl(h, base32 + half*8 + i, 64) * ac[i];
    float tt = part + __shfl_xor(part, 16, 64);
    h = tt + gu;
    if (!(lane & 16))
      hs2[((size_t)(p0 + l2*stride))*64 + off + s] = (unsigned short)f2bf(h);
    gu = gu_next;
  }
}

// ---------------- fused: 384c x 64p; K split in 2 halves over ONE 24KB buffer ----------
// grid 1024 = (b, pt) XCD-swizzled; 8 waves (512 thr); wave w: c-rows w*48 + mi*16
// 24KB LDS; launch_bounds(512,4) -> natural ~64-80 VGPR, up to 4 blocks/CU (r13 proved 71% occ)
__global__ __launch_bounds__(512, 4) void k_fused(
    const unsigned short* __restrict__ xbf,
    const unsigned short* __restrict__ WsumBf,
    const unsigned short* __restrict__ h1bf, const unsigned short* __restrict__ g2wBf,
    const unsigned short* __restrict__ hs2, const unsigned short* __restrict__ WocatBf,
    const float* __restrict__ g2b,
    const float* __restrict__ boR, const float* __restrict__ bsR,
    const float* __restrict__ boC, const float* __restrict__ bsC,
    float* __restrict__ outp)
{
  int obid = blockIdx.x;
  int bid = ((obid & 7) * 128) + (obid >> 3);   // 1024 = 8*128 bijective
  int b = bid >> 6, pt = bid & 63;
  int t = threadIdx.x;
  int w = t >> 6, l = t & 63;
  int lr = l & 15, kq = l >> 4, kb8 = kq * 8;
  int cw = w*48;

  __shared__ unsigned short xt[64*24*8];    // 24KB: granule (p,kgs) at p*24+kgs; one K-half

  const unsigned short* xrow0 = xbf + ((size_t)(b*PP + pt*64))*CCH;

  // ---- gate operand loads ----
  short8 gaw[3][2], gbv[2][4];
  {
    const unsigned short* hbase = h1bf + ((size_t)(b*PP + pt*64 + lr))*64 + kb8;
    #pragma unroll
    for (int ks=0; ks<2; ++ks)
      #pragma unroll
      for (int nf=0; nf<4; ++nf)
        gbv[ks][nf] = *(const short8*)(hbase + (size_t)nf*16*64 + ks*32);
    #pragma unroll
    for (int mi=0; mi<3; ++mi){
      const unsigned short* wbg = g2wBf + (size_t)(cw + mi*16 + lr)*64 + kb8;
      gaw[mi][0] = *(const short8*)(wbg);
      gaw[mi][1] = *(const short8*)(wbg + 32);
    }
  }

  // ---- stage half0 (c 0..191): 1536 granules, 3 issues/thread ----
  #pragma unroll
  for (int i=0;i<3;++i){
    int G = w*192 + i*64 + l;
    int p = G/24, kgs = G - p*24;
    int kg = (kgs & ~7) | ((kgs & 7) ^ (p & 7));
    gload_lds16(xrow0 + (size_t)p*CCH + kg*8, &xt[(size_t)G*8]);
  }

  // ---- gate MFMAs + fast sigmoid + f16 pack (under stage-0 flight) ----
  unsigned int gt[3][4][2];
  {
    f32x4 gac[3][4] = {};
    #pragma unroll
    for (int ks=0; ks<2; ++ks)
      #pragma unroll
      for (int nf=0; nf<4; ++nf)
        #pragma unroll
        for (int mi=0; mi<3; ++mi)
          gac[mi][nf] = __builtin_amdgcn_mfma_f32_16x16x32_bf16(gaw[mi][ks], gbv[ks][nf], gac[mi][nf], 0,0,0);
    #pragma unroll
    for (int mi=0;mi<3;++mi){
      float4 gb4 = *(const float4*)&g2b[cw + mi*16 + kq*4];
      #pragma unroll
      for (int nf=0;nf<4;++nf){
        float s0 = fast_sig(gac[mi][nf][0] + gb4.x);
        float s1 = fast_sig(gac[mi][nf][1] + gb4.y);
        float s2 = fast_sig(gac[mi][nf][2] + gb4.z);
        float s3 = fast_sig(gac[mi][nf][3] + gb4.w);
        half2t p01 = __builtin_amdgcn_cvt_pkrtz(s0, s1);
        half2t p23 = __builtin_amdgcn_cvt_pkrtz(s2, s3);
        __builtin_memcpy(&gt[mi][nf][0], &p01, 4);
        __builtin_memcpy(&gt[mi][nf][1], &p23, 4);
      }
    }
  }

  __syncthreads();   // half0 resident

  f32x4 acc[3][4] = {};
  const unsigned short* wbS = WsumBf + (size_t)(cw + lr)*CCH + kb8;
  int cb0q = cw + kq*4;              // this thread's first c-row (mi=0)
  uint2 xresAll[3][4];

  // ---- K loop half0: global chunks 0..2 ----
  #pragma unroll
  for (int c=0;c<3;++c){
    short8 a[3][2];
    #pragma unroll
    for (int mi=0;mi<3;++mi){
      a[mi][0] = *(const short8*)(wbS + (size_t)mi*16*CCH + c*64);
      a[mi][1] = *(const short8*)(wbS + (size_t)mi*16*CCH + c*64 + 32);
    }
    #pragma unroll
    for (int ks=0;ks<2;++ks){
      int kgl = ks*4 + kq;
      #pragma unroll
      for (int nf=0;nf<4;++nf){
        int pr = nf*16 + lr;
        int kgs = c*8 + (kgl ^ (pr & 7));
        short8 bv = *(const short8*)&xt[(size_t)(pr*24 + kgs)*8];
        #pragma unroll
        for (int mi=0;mi<3;++mi)
          acc[mi][nf] = __builtin_amdgcn_mfma_f32_16x16x32_bf16(a[mi][ks], bv, acc[mi][nf], 0,0,0);
      }
    }
  }
  // residual rows for waves 0..3 live in half0 (c < 192)
  if (w < 4) {
    #pragma unroll
    for (int mi=0;mi<3;++mi){
      int cb0 = cb0q + mi*16;
      int kgR = cb0 >> 3, eoff = cb0 & 7;
      #pragma unroll
      for (int nf=0;nf<4;++nf){
        int p = nf*16 + lr;
        int kgsR = (kgR & ~7) | ((kgR & 7) ^ (p & 7));
        xresAll[mi][nf] = *(const uint2*)&xt[(size_t)(p*24 + kgsR)*8 + eoff];
      }
    }
  }

  __syncthreads();   // all half0 reads done -> safe to overwrite

  // ---- stage half1 (c 192..383) ----
  #pragma unroll
  for (int i=0;i<3;++i){
    int G = w*192 + i*64 + l;
    int p = G/24, kgs = G - p*24;
    int kg = (kgs & ~7) | ((kgs & 7) ^ (p & 7));
    gload_lds16(xrow0 + (size_t)p*CCH + 192 + kg*8, &xt[(size_t)G*8]);
  }

  __syncthreads();   // half1 resident

  // ---- K loop half1: global chunks 3..5 (local 0..2) ----
  #pragma unroll
  for (int c=0;c<3;++c){
    short8 a[3][2];
    #pragma unroll
    for (int mi=0;mi<3;++mi){
      a[mi][0] = *(const short8*)(wbS + (size_t)mi*16*CCH + (c+3)*64);
      a[mi][1] = *(const short8*)(wbS + (size_t)mi*16*CCH + (c+3)*64 + 32);
    }
    #pragma unroll
    for (int ks=0;ks<2;++ks){
      int kgl = ks*4 + kq;
      #pragma unroll
      for (int nf=0;nf<4;++nf){
        int pr = nf*16 + lr;
        int kgs = c*8 + (kgl ^ (pr & 7));
        short8 bv = *(const short8*)&xt[(size_t)(pr*24 + kgs)*8];
        #pragma unroll
        for (int mi=0;mi<3;++mi)
          acc[mi][nf] = __builtin_amdgcn_mfma_f32_16x16x32_bf16(a[mi][ks], bv, acc[mi][nf], 0,0,0);
      }
    }
  }
  // residual rows for waves 4..7 live in half1
  if (w >= 4) {
    #pragma unroll
    for (int mi=0;mi<3;++mi){
      int cb0 = cb0q + mi*16 - 192;
      int kgR = cb0 >> 3, eoff = cb0 & 7;
      #pragma unroll
      for (int nf=0;nf<4;++nf){
        int p = nf*16 + lr;
        int kgsR = (kgR & ~7) | ((kgR & 7) ^ (p & 7));
        xresAll[mi][nf] = *(const uint2*)&xt[(size_t)(p*24 + kgsR)*8 + eoff];
      }
    }
  }

  // ---- phase C: K=64 over [hfR|hfC|hbR|hbC] with 0.5-scaled Wocat, into acc ----
  {
    const unsigned short* hb2 = hs2 + ((size_t)(b*PP + pt*64 + lr))*64 + kb8;
    short8 hv[2][4];
    #pragma unroll
    for (int ks=0;ks<2;++ks)
      #pragma unroll
      for (int nf=0;nf<4;++nf)
        hv[ks][nf] = *(const short8*)(hb2 + (size_t)nf*16*64 + ks*32);
    #pragma unroll
    for (int mi=0;mi<3;++mi){
      const unsigned short* wo = WocatBf + (size_t)(cw + mi*16 + lr)*64 + kb8;
      short8 wa0 = *(const short8*)(wo);
      short8 wa1 = *(const short8*)(wo + 32);
      #pragma unroll
      for (int nf=0;nf<4;++nf){
        acc[mi][nf] = __builtin_amdgcn_mfma_f32_16x16x32_bf16(wa0, hv[0][nf], acc[mi][nf], 0,0,0);
        acc[mi][nf] = __builtin_amdgcn_mfma_f32_16x16x32_bf16(wa1, hv[1][nf], acc[mi][nf], 0,0,0);
      }
    }
  }

  // ---- epilogue: y = 0.5*acc + 0.5*(bias sums); residual from xresAll; gt unpack ----
  #pragma unroll
  for (int mi=0;mi<3;++mi){
    int cb0 = cw + mi*16 + kq*4;
    float4 b1 = *(const float4*)&boR[cb0];
    float4 b2 = *(const float4*)&bsR[cb0];
    float4 b3 = *(const float4*)&boC[cb0];
    float4 b4 = *(const float4*)&bsC[cb0];
    float cb4[4] = { b1.x+b2.x+b3.x+b4.x, b1.y+b2.y+b3.y+b4.y,
                     b1.z+b2.z+b3.z+b4.z, b1.w+b2.w+b3.w+b4.w };
    #pragma unroll
    for (int nf=0;nf<4;++nf){
      int p = nf*16 + lr;
      uint2 xr = xresAll[mi][nf];
      half2t g01, g23;
      __builtin_memcpy(&g01, &gt[mi][nf][0], 4);
      __builtin_memcpy(&g23, &gt[mi][nf][1], 4);
      float gv[4] = { (float)g01[0], (float)g01[1], (float)g23[0], (float)g23[1] };
      #pragma unroll
      for (int r=0;r<4;++r){
        unsigned int word = (r < 2) ? xr.x : xr.y;
        unsigned short us = (r & 1) ? (unsigned short)(word >> 16) : (unsigned short)(word & 0xffff);
        float xv = bf2f(us);
        float y = 0.5f*acc[mi][nf][r] + 0.5f*cb4[r];
        float gtv = gv[r];
        size_t addr = ((size_t)(b*CCH + cb0 + r))*PP + pt*64 + p;
        outp[addr] = gtv*y + (1.f-gtv)*xv;
      }
    }
  }
}

extern "C" void kernel_launch(void* const* d_in, const int* in_sizes, int n_in,
                              void* d_out, int out_size, void* d_ws, size_t ws_size,
                              hipStream_t stream)
{
  const float* x    = (const float*)d_in[0];
  const float* rAl  = (const float*)d_in[1];
  const float* rU   = (const float*)d_in[2];
  const float* rV   = (const float*)d_in[3];
  const float* rWin = (const float*)d_in[4];
  const float* rbin = (const float*)d_in[5];
  const float* rWg  = (const float*)d_in[6];
  const float* rbg  = (const float*)d_in[7];
  const float* rWo  = (const float*)d_in[8];
  const float* rbo  = (const float*)d_in[9];
  const float* rWs  = (const float*)d_in[10];
  const float* rbs  = (const float*)d_in[11];
  const float* cAl  = (const float*)d_in[12];
  const float* cU   = (const float*)d_in[13];
  const float* cV   = (const float*)d_in[14];
  const float* cWin = (const float*)d_in[15];
  const float* cbin = (const float*)d_in[16];
  const float* cWg  = (const float*)d_in[17];
  const float* cbg  = (const float*)d_in[18];
  const float* cWo  = (const float*)d_in[19];
  const float* cbo  = (const float*)d_in[20];
  const float* cWs  = (const float*)d_in[21];
  const float* cbs  = (const float*)d_in[22];
  const float* g1w  = (const float*)d_in[23];
  const float* g1b  = (const float*)d_in[24];
  const float* g2w  = (const float*)d_in[25];
  const float* g2b  = (const float*)d_in[26];
  const float* nw   = (const float*)d_in[27];
  const float* nb   = (const float*)d_in[28];

  float* ws   = (float*)d_ws;
  float* ugr  = ws;                    // 1048576 (B,P,16) fp32
  float* ugc  = ugr + 1048576;         // 1048576
  float* Arow = ugc + 1048576;         // 256
  float* Acol = Arow + 256;            // 256
  float* t1   = Acol + 256;            // 64
  float* t2   = t1 + 64;               // 64
  unsigned short* xbf     = (unsigned short*)(t2 + 64);   // 16*4096*384 = 25165824
  unsigned short* h1bf    = xbf + (size_t)25165824;       // 16*4096*64  = 4194304
  unsigned short* hs2     = h1bf + (size_t)4194304;       // 16*4096*64  = 4194304
  unsigned short* WsumBf  = hs2 + (size_t)4194304;        // 147456
  unsigned short* WcatBf  = WsumBf + 147456;              // 49152
  unsigned short* g2wBf   = WcatBf + 49152;               // 24576
  unsigned short* WocatBf = g2wBf + 24576;                // 24576
  float* outp = (float*)d_out;

  k_prep<<<961, 256, 0, stream>>>(rAl,rU,rV,cAl,cU,cV,rWs,cWs,
                                  rWin,rWg,cWin,cWg,g1w,nw,nb,g2w,rWo,cWo,
                                  Arow,Acol,WsumBf,WcatBf,g2wBf,WocatBf,t1,t2);
  k_xf<<<1024, 256, 0, stream>>>(x, WcatBf, rbin, rbg, cbin, cbg,
                                 t1, t2, g1b, xbf, ugr, ugc, h1bf);
  k_scan<<<512, 256, 0, stream>>>(ugr, ugc, Arow, Acol, hs2);
  k_fused<<<1024, 512, 0, stream>>>(xbf, WsumBf, h1bf, g2wBf,
                                    hs2, WocatBf, g2b,
                                    rbo, rbs, cbo, cbs, outp);
}

// Round 15
// 152.432 us; speedup vs baseline: 3.5629x; 1.4554x over previous
//
#include <hip/hip_runtime.h>
#include <hip/hip_bf16.h>
#include <math.h>

#define PP 4096      // H*W
#define CCH 384      // channels
#define NB 16        // batch

using short8 = __attribute__((ext_vector_type(8))) short;
using f32x4  = __attribute__((ext_vector_type(4))) float;
using half2t = __attribute__((ext_vector_type(2))) __fp16;

__device__ __forceinline__ float sigmoidf_(float v){ return 1.f/(1.f+expf(-v)); }
__device__ __forceinline__ float fast_sig(float v){
  return __builtin_amdgcn_rcpf(1.f + __builtin_amdgcn_exp2f(-v*1.44269504088896f));
}
__device__ __forceinline__ unsigned int f2bf(float f){
  __hip_bfloat16 h = __float2bfloat16(f);
  return (unsigned int)*reinterpret_cast<unsigned short*>(&h);
}
__device__ __forceinline__ float bf2f(unsigned short u){
  unsigned int w = ((unsigned int)u) << 16;
  return __uint_as_float(w);
}
__device__ __forceinline__ void gload_lds16(const void* g, void* l){
  __builtin_amdgcn_global_load_lds(
      (const __attribute__((address_space(1))) unsigned int*)g,
      (__attribute__((address_space(3))) unsigned int*)l, 16, 0, 0);
}

// ---------------- prep ----------------
// grid 961: [0,576) WsumBf; [576,768) WcatBf; [768,864) g2wBf; [864,960) Wocat64 (x0.5); 960: A+t1/t2
__global__ __launch_bounds__(256) void k_prep(
    const float* __restrict__ rAl, const float* __restrict__ rU, const float* __restrict__ rV,
    const float* __restrict__ cAl, const float* __restrict__ cU, const float* __restrict__ cV,
    const float* __restrict__ rWs, const float* __restrict__ cWs,
    const float* __restrict__ WinR, const float* __restrict__ WgR,
    const float* __restrict__ WinC, const float* __restrict__ WgC,
    const float* __restrict__ g1w, const float* __restrict__ nw, const float* __restrict__ nb,
    const float* __restrict__ g2w,
    const float* __restrict__ WoR, const float* __restrict__ WoC,
    float* __restrict__ Arow, float* __restrict__ Acol,
    unsigned short* __restrict__ WsumBf, unsigned short* __restrict__ WcatBf,
    unsigned short* __restrict__ g2wBf, unsigned short* __restrict__ WocatBf,
    float* __restrict__ t1, float* __restrict__ t2)
{
  int bid = blockIdx.x, tid = threadIdx.x;
  if (bid < 576) {
    int idx = bid*256 + tid;
    WsumBf[idx] = (unsigned short)f2bf(rWs[idx] + cWs[idx]);
  } else if (bid < 768) {
    int idx = (bid-576)*256 + tid;
    int row = idx / CCH, col = idx - row*CCH;
    float v;
    if      (row < 16)  v = WinR[row*CCH + col];
    else if (row < 32)  v = WgR [(row-16)*CCH + col];
    else if (row < 48)  v = WinC[(row-32)*CCH + col];
    else if (row < 64)  v = WgC [(row-48)*CCH + col];
    else                v = g1w[(row-64)*CCH + col]*nw[col];
    WcatBf[idx] = (unsigned short)f2bf(v);
  } else if (bid < 864) {
    int idx = (bid-768)*256 + tid;
    g2wBf[idx] = (unsigned short)f2bf(g2w[idx]);
  } else if (bid < 960) {
    int idx = (bid-864)*256 + tid;   // [0, 24576): (c, k) k in 0..63
    int c = idx >> 6, k = idx & 63;
    int sel = (k >> 4) & 1;          // 0:WoR 1:WoC, duplicated for fwd/bwd halves
    float v = 0.5f * (sel ? WoC[c*16 + (k&15)] : WoR[c*16 + (k&15)]);
    WocatBf[idx] = (unsigned short)f2bf(v);
  } else {
    {
      int i = tid >> 4, j = tid & 15;
      float sr = 0.f, sc = 0.f;
      #pragma unroll
      for (int r=0;r<8;++r){ sr += rV[i*8+r]*rU[j*8+r]; sc += cV[i*8+r]*cU[j*8+r]; }
      if (i==j){ sr += sigmoidf_(rAl[i]); sc += sigmoidf_(cAl[i]); }
      Arow[tid] = sr; Acol[tid] = sc;
    }
    if (tid < 64) {
      float s1=0.f, s2=0.f;
      for (int c=0;c<CCH;++c){ s1 += g1w[tid*CCH+c]*nw[c]; s2 += nb[c]*g1w[tid*CCH+c]; }
      t1[tid]=s1; t2[tid]=s2;
    }
  }
}

// ---------------- xf: transpose + bf16 + stats + front MFMA GEMM ----------------
__global__ __launch_bounds__(256) void k_xf(
    const float* __restrict__ x, const unsigned short* __restrict__ WcatBf,
    const float* __restrict__ binR, const float* __restrict__ bgR,
    const float* __restrict__ binC, const float* __restrict__ bgC,
    const float* __restrict__ t1, const float* __restrict__ t2,
    const float* __restrict__ g1b,
    unsigned short* __restrict__ xbf,
    float* __restrict__ ugr, float* __restrict__ ugc,
    unsigned short* __restrict__ h1bf)
{
  int b = blockIdx.x >> 6, pt = blockIdx.x & 63;
  int t = threadIdx.x;
  int w = t >> 6, l = t & 63;
  int lr = l & 15, kq = l >> 4, kb8 = kq*8;
  int pl = t & 63, g4 = w;

  __shared__ unsigned short xtb[64*64];
  __shared__ float red[512];
  __shared__ float meanS[64], invS[64];

  const float* xb = x + (size_t)b*CCH*PP + pt*64;
  f32x4 acc[2][4] = {};
  float sx = 0.f, sx2 = 0.f;

  float xv[16];
  #pragma unroll
  for (int j=0;j<16;++j) xv[j] = xb[(size_t)(g4*16 + j)*PP + pl];

  const unsigned short* wrow0 = WcatBf + (size_t)(w*32 + lr)*CCH + kb8;
  const unsigned short* wrow1 = wrow0 + 16*CCH;
  unsigned short* xgo = xbf + ((size_t)(b*PP + pt*64))*CCH;

  #pragma unroll
  for (int cc=0; cc<6; ++cc) {
    unsigned int pk[8];
    #pragma unroll
    for (int j=0;j<16;++j){ sx += xv[j]; sx2 += xv[j]*xv[j]; }
    #pragma unroll
    for (int j=0;j<8;++j) pk[j] = f2bf(xv[2*j]) | (f2bf(xv[2*j+1])<<16);
    __syncthreads();
    {
      int kg0 = g4*2, kg1 = g4*2+1;
      uint4 v0 = make_uint4(pk[0],pk[1],pk[2],pk[3]);
      uint4 v1 = make_uint4(pk[4],pk[5],pk[6],pk[7]);
      *(uint4*)&xtb[(size_t)(pl*8 + (kg0 ^ (pl&7)))*8] = v0;
      *(uint4*)&xtb[(size_t)(pl*8 + (kg1 ^ (pl&7)))*8] = v1;
    }
    if (cc < 5) {
      #pragma unroll
      for (int j=0;j<16;++j) xv[j] = xb[(size_t)((cc+1)*64 + g4*16 + j)*PP + pl];
    }
    short8 a0k0 = *(const short8*)(wrow0 + cc*64);
    short8 a0k1 = *(const short8*)(wrow0 + cc*64 + 32);
    short8 a1k0 = *(const short8*)(wrow1 + cc*64);
    short8 a1k1 = *(const short8*)(wrow1 + cc*64 + 32);
    __syncthreads();
    #pragma unroll
    for (int ks=0; ks<2; ++ks){
      int kg = ks*4 + kq;
      #pragma unroll
      for (int nf=0; nf<4; ++nf){
        int pr = nf*16 + lr;
        short8 bv = *(const short8*)&xtb[(size_t)(pr*8 + (kg ^ (pr&7)))*8];
        acc[0][nf] = __builtin_amdgcn_mfma_f32_16x16x32_bf16(ks? a0k1:a0k0, bv, acc[0][nf], 0,0,0);
        acc[1][nf] = __builtin_amdgcn_mfma_f32_16x16x32_bf16(ks? a1k1:a1k0, bv, acc[1][nf], 0,0,0);
      }
    }
    #pragma unroll
    for (int it=0; it<2; ++it){
      int p2 = 32*it + (t>>3), kg2 = t & 7;
      uint4 v = *(const uint4*)&xtb[(size_t)(p2*8 + (kg2 ^ (p2&7)))*8];
      *(uint4*)&xgo[(size_t)p2*CCH + cc*64 + kg2*8] = v;
    }
  }

  __syncthreads();
  red[g4*64 + pl] = sx;
  red[256 + g4*64 + pl] = sx2;
  __syncthreads();
  if (t < 64) {
    float s1 = red[t] + red[64+t] + red[128+t] + red[192+t];
    float s2 = red[256+t] + red[320+t] + red[384+t] + red[448+t];
    float mu = s1 * (1.f/CCH);
    float var = s2 * (1.f/CCH) - mu*mu;
    meanS[t] = mu;
    invS[t]  = rsqrtf(var + 1e-6f);
  }
  __syncthreads();

  if (w < 2) {
    const float* bu = w ? binC : binR;
    const float* bg = w ? bgC  : bgR;
    float* dst = w ? ugc : ugr;
    float bus[4], bgs[4];
    #pragma unroll
    for (int r=0;r<4;++r){ int s = kq*4 + r; bus[r]=bu[s]; bgs[r]=bg[s]; }
    #pragma unroll
    for (int nf=0; nf<4; ++nf){
      size_t pbase = ((size_t)(b*PP + pt*64 + nf*16 + lr))*16;
      #pragma unroll
      for (int r=0;r<4;++r){
        int s = kq*4 + r;
        float u = acc[0][nf][r] + bus[r];
        float g = fast_sig(acc[1][nf][r] + bgs[r]);
        dst[pbase + s] = u*g;
      }
    }
  } else {
    int ob = (w-2)*32 + kq*4;
    float t1o[2][4], t2o[2][4], gbo[2][4];
    #pragma unroll
    for (int mi=0;mi<2;++mi)
      #pragma unroll
      for (int r=0;r<4;++r){
        int o = ob + mi*16 + r;
        t1o[mi][r]=t1[o]; t2o[mi][r]=t2[o]; gbo[mi][r]=g1b[o];
      }
    #pragma unroll
    for (int nf=0; nf<4; ++nf){
      int pLoc = nf*16 + lr;
      float mu = meanS[pLoc], iv = invS[pLoc];
      #pragma unroll
      for (int mi=0;mi<2;++mi){
        unsigned int us[4];
        #pragma unroll
        for (int r=0;r<4;++r){
          float pre = iv*(acc[mi][nf][r] - mu*t1o[mi][r]) + t2o[mi][r] + gbo[mi][r];
          float ge = 0.5f*pre*(1.f + erff(pre*0.70710678118654752f));
          us[r] = f2bf(ge);
        }
        uint2 o2; o2.x = us[0] | (us[1]<<16); o2.y = us[2] | (us[3]<<16);
        *reinterpret_cast<uint2*>(h1bf + ((size_t)(b*PP + pt*64 + pLoc))*64 + (w-2)*32 + mi*16 + kq*4) = o2;
      }
    }
  }
}

// ---------------- scan: 4096 independent (dir,seq) tasks; hs2 (B,P,64)=[hfR|hfC|hbR|hbC] ----
// grid 256 x 256 (4 waves); 4 tasks per wave (16 lanes each)
__global__ __launch_bounds__(256) void k_scan(
    const float* __restrict__ ugr, const float* __restrict__ ugc,
    const float* __restrict__ Arow, const float* __restrict__ Acol,
    unsigned short* __restrict__ hs2)
{
  int W = blockIdx.x*4 + (threadIdx.x >> 6);
  int lane = threadIdx.x & 63;
  int tsk = W*4 + (lane >> 4);
  int s = lane & 15, base = lane & 48;
  int dir = tsk >> 11;
  int rem = tsk & 2047;
  int isCol = rem >> 10;
  int gg = rem & 1023;
  int b = gg >> 6, rc = gg & 63;
  const float* ug = isCol ? ugc : ugr;
  const float* A  = isCol ? Acol : Arow;
  int off = dir*32 + isCol*16;
  int p0 = b*PP + (isCol ? rc : rc*64);
  int stride = isCol ? 64 : 1;
  float ac[16];
  #pragma unroll
  for (int i=0;i<16;++i) ac[i] = A[i*16 + s];
  float h = 0.f;
  #pragma unroll 4
  for (int st=0; st<64; ++st){
    int l2 = dir ? (63-st) : st;
    float gu = ug[((size_t)(p0 + l2*stride))*16 + s];
    float tt = 0.f;
    #pragma unroll
    for (int i=0;i<16;++i) tt += __shfl(h, base + i, 64) * ac[i];
    h = tt + gu;
    hs2[((size_t)(p0 + l2*stride))*64 + off + s] = (unsigned short)f2bf(h);
  }
}

// ---------------- fused: 384-c block; full-tile LDS; 3 m-frags/wave; phaseC folded into acc ----
// grid 1024 = (b, pt) XCD-swizzled; 8 waves (512 thr); wave w: c-rows w*48 + mi*16
__global__ __launch_bounds__(512, 4) void k_fused(
    const unsigned short* __restrict__ xbf,
    const unsigned short* __restrict__ WsumBf,
    const unsigned short* __restrict__ h1bf, const unsigned short* __restrict__ g2wBf,
    const unsigned short* __restrict__ hs2, const unsigned short* __restrict__ WocatBf,
    const float* __restrict__ g2b,
    const float* __restrict__ boR, const float* __restrict__ bsR,
    const float* __restrict__ boC, const float* __restrict__ bsC,
    float* __restrict__ outp)
{
  int obid = blockIdx.x;
  int bid = ((obid & 7) * 128) + (obid >> 3);   // 1024 = 8*128 bijective
  int b = bid >> 6, pt = bid & 63;
  int t = threadIdx.x;
  int w = t >> 6, l = t & 63;
  int lr = l & 15, kq = l >> 4, kb8 = kq * 8;
  int cw = w*48;

  __shared__ unsigned short xt[64*48*8];    // 48KB

  // ---- gate operand loads (oldest VMEM) ----
  short8 gaw[3][2], gbv[2][4];
  {
    const unsigned short* hbase = h1bf + ((size_t)(b*PP + pt*64 + lr))*64 + kb8;
    #pragma unroll
    for (int ks=0; ks<2; ++ks)
      #pragma unroll
      for (int nf=0; nf<4; ++nf)
        gbv[ks][nf] = *(const short8*)(hbase + (size_t)nf*16*64 + ks*32);
    #pragma unroll
    for (int mi=0; mi<3; ++mi){
      const unsigned short* wbg = g2wBf + (size_t)(cw + mi*16 + lr)*64 + kb8;
      gaw[mi][0] = *(const short8*)(wbg);
      gaw[mi][1] = *(const short8*)(wbg + 32);
    }
  }

  // ---- bulk stage: whole 48KB tile, 6 issues/wave ----
  {
    const unsigned short* xrow0 = xbf + ((size_t)(b*PP + pt*64))*CCH;
    #pragma unroll
    for (int i=0;i<6;++i){
      int G = w*384 + i*64 + l;
      int p = G/48, kgs = G - p*48;
      int kg = (kgs & ~7) | ((kgs & 7) ^ (p & 7));
      gload_lds16(xrow0 + (size_t)p*CCH + kg*8, &xt[(size_t)G*8]);
    }
  }

  // ---- gate MFMAs + fast sigmoid + f16 pack ----
  unsigned int gt[3][4][2];
  {
    f32x4 gac[3][4] = {};
    #pragma unroll
    for (int ks=0; ks<2; ++ks)
      #pragma unroll
      for (int nf=0; nf<4; ++nf)
        #pragma unroll
        for (int mi=0; mi<3; ++mi)
          gac[mi][nf] = __builtin_amdgcn_mfma_f32_16x16x32_bf16(gaw[mi][ks], gbv[ks][nf], gac[mi][nf], 0,0,0);
    #pragma unroll
    for (int mi=0;mi<3;++mi){
      float4 gb4 = *(const float4*)&g2b[cw + mi*16 + kq*4];
      #pragma unroll
      for (int nf=0;nf<4;++nf){
        float s0 = fast_sig(gac[mi][nf][0] + gb4.x);
        float s1 = fast_sig(gac[mi][nf][1] + gb4.y);
        float s2 = fast_sig(gac[mi][nf][2] + gb4.z);
        float s3 = fast_sig(gac[mi][nf][3] + gb4.w);
        half2t p01 = __builtin_amdgcn_cvt_pkrtz(s0, s1);
        half2t p23 = __builtin_amdgcn_cvt_pkrtz(s2, s3);
        __builtin_memcpy(&gt[mi][nf][0], &p01, 4);
        __builtin_memcpy(&gt[mi][nf][1], &p23, 4);
      }
    }
  }

  __syncthreads();   // ONE barrier: tile resident

  // ---- skip K loop: 6 chunks; 8 ds_reads -> 24 MFMAs per chunk per wave ----
  f32x4 acc[3][4] = {};
  const unsigned short* wbS = WsumBf + (size_t)(cw + lr)*CCH + kb8;
  #pragma unroll
  for (int c=0;c<6;++c){
    short8 a[3][2];
    #pragma unroll
    for (int mi=0;mi<3;++mi){
      a[mi][0] = *(const short8*)(wbS + (size_t)mi*16*CCH + c*64);
      a[mi][1] = *(const short8*)(wbS + (size_t)mi*16*CCH + c*64 + 32);
    }
    #pragma unroll
    for (int ks=0;ks<2;++ks){
      int kgl = ks*4 + kq;
      #pragma unroll
      for (int nf=0;nf<4;++nf){
        int pr = nf*16 + lr;
        int kgs = c*8 + (kgl ^ (pr & 7));
        short8 bv = *(const short8*)&xt[(size_t)(pr*48 + kgs)*8];
        #pragma unroll
        for (int mi=0;mi<3;++mi)
          acc[mi][nf] = __builtin_amdgcn_mfma_f32_16x16x32_bf16(a[mi][ks], bv, acc[mi][nf], 0,0,0);
      }
    }
  }

  // ---- phase C: K=64 over [hfR|hfC|hbR|hbC] with 0.5-scaled Wocat, into acc ----
  {
    const unsigned short* hb2 = hs2 + ((size_t)(b*PP + pt*64 + lr))*64 + kb8;
    short8 hv[2][4];
    #pragma unroll
    for (int ks=0;ks<2;++ks)
      #pragma unroll
      for (int nf=0;nf<4;++nf)
        hv[ks][nf] = *(const short8*)(hb2 + (size_t)nf*16*64 + ks*32);
    #pragma unroll
    for (int mi=0;mi<3;++mi){
      const unsigned short* wo = WocatBf + (size_t)(cw + mi*16 + lr)*64 + kb8;
      short8 wa0 = *(const short8*)(wo);
      short8 wa1 = *(const short8*)(wo + 32);
      #pragma unroll
      for (int nf=0;nf<4;++nf){
        acc[mi][nf] = __builtin_amdgcn_mfma_f32_16x16x32_bf16(wa0, hv[0][nf], acc[mi][nf], 0,0,0);
        acc[mi][nf] = __builtin_amdgcn_mfma_f32_16x16x32_bf16(wa1, hv[1][nf], acc[mi][nf], 0,0,0);
      }
    }
  }

  // ---- epilogue: y = 0.5*acc + 0.5*(bo+bs sums); residual from LDS; gt unpack ----
  #pragma unroll
  for (int mi=0;mi<3;++mi){
    int cb0 = cw + mi*16 + kq*4;
    float4 b1 = *(const float4*)&boR[cb0];
    float4 b2 = *(const float4*)&bsR[cb0];
    float4 b3 = *(const float4*)&boC[cb0];
    float4 b4 = *(const float4*)&bsC[cb0];
    float cb4[4] = { b1.x+b2.x+b3.x+b4.x, b1.y+b2.y+b3.y+b4.y,
                     b1.z+b2.z+b3.z+b4.z, b1.w+b2.w+b3.w+b4.w };
    int kgR = cb0 >> 3, eoff = cb0 & 7;       // eoff in {0,4}
    #pragma unroll
    for (int nf=0;nf<4;++nf){
      int p = nf*16 + lr;
      int kgsR = (kgR & ~7) | ((kgR & 7) ^ (p & 7));
      uint2 xres = *(const uint2*)&xt[(size_t)(p*48 + kgsR)*8 + eoff];
      half2t g01, g23;
      __builtin_memcpy(&g01, &gt[mi][nf][0], 4);
      __builtin_memcpy(&g23, &gt[mi][nf][1], 4);
      float gv[4] = { (float)g01[0], (float)g01[1], (float)g23[0], (float)g23[1] };
      #pragma unroll
      for (int r=0;r<4;++r){
        unsigned int word = (r < 2) ? xres.x : xres.y;
        unsigned short us = (r & 1) ? (unsigned short)(word >> 16) : (unsigned short)(word & 0xffff);
        float xv = bf2f(us);
        float y = 0.5f*acc[mi][nf][r] + 0.5f*cb4[r];
        float gtv = gv[r];
        size_t addr = ((size_t)(b*CCH + cb0 + r))*PP + pt*64 + p;
        outp[addr] = gtv*y + (1.f-gtv)*xv;
      }
    }
  }
}

extern "C" void kernel_launch(void* const* d_in, const int* in_sizes, int n_in,
                              void* d_out, int out_size, void* d_ws, size_t ws_size,
                              hipStream_t stream)
{
  const float* x    = (const float*)d_in[0];
  const float* rAl  = (const float*)d_in[1];
  const float* rU   = (const float*)d_in[2];
  const float* rV   = (const float*)d_in[3];
  const float* rWin = (const float*)d_in[4];
  const float* rbin = (const float*)d_in[5];
  const float* rWg  = (const float*)d_in[6];
  const float* rbg  = (const float*)d_in[7];
  const float* rWo  = (const float*)d_in[8];
  const float* rbo  = (const float*)d_in[9];
  const float* rWs  = (const float*)d_in[10];
  const float* rbs  = (const float*)d_in[11];
  const float* cAl  = (const float*)d_in[12];
  const float* cU   = (const float*)d_in[13];
  const float* cV   = (const float*)d_in[14];
  const float* cWin = (const float*)d_in[15];
  const float* cbin = (const float*)d_in[16];
  const float* cWg  = (const float*)d_in[17];
  const float* cbg  = (const float*)d_in[18];
  const float* cWo  = (const float*)d_in[19];
  const float* cbo  = (const float*)d_in[20];
  const float* cWs  = (const float*)d_in[21];
  const float* cbs  = (const float*)d_in[22];
  const float* g1w  = (const float*)d_in[23];
  const float* g1b  = (const float*)d_in[24];
  const float* g2w  = (const float*)d_in[25];
  const float* g2b  = (const float*)d_in[26];
  const float* nw   = (const float*)d_in[27];
  const float* nb   = (const float*)d_in[28];

  float* ws   = (float*)d_ws;
  float* ugr  = ws;                    // 1048576 (B,P,16) fp32
  float* ugc  = ugr + 1048576;         // 1048576
  float* Arow = ugc + 1048576;         // 256
  float* Acol = Arow + 256;            // 256
  float* t1   = Acol + 256;            // 64
  float* t2   = t1 + 64;               // 64
  unsigned short* xbf     = (unsigned short*)(t2 + 64);   // 16*4096*384 = 25165824
  unsigned short* h1bf    = xbf + (size_t)25165824;       // 16*4096*64  = 4194304
  unsigned short* hs2     = h1bf + (size_t)4194304;       // 16*4096*64  = 4194304
  unsigned short* WsumBf  = hs2 + (size_t)4194304;        // 147456
  unsigned short* WcatBf  = WsumBf + 147456;              // 49152
  unsigned short* g2wBf   = WcatBf + 49152;               // 24576
  unsigned short* WocatBf = g2wBf + 24576;                // 24576
  float* outp = (float*)d_out;

  k_prep<<<961, 256, 0, stream>>>(rAl,rU,rV,cAl,cU,cV,rWs,cWs,
                                  rWin,rWg,cWin,cWg,g1w,nw,nb,g2w,rWo,cWo,
                                  Arow,Acol,WsumBf,WcatBf,g2wBf,WocatBf,t1,t2);
  k_xf<<<1024, 256, 0, stream>>>(x, WcatBf, rbin, rbg, cbin, cbg,
                                 t1, t2, g1b, xbf, ugr, ugc, h1bf);
  k_scan<<<256, 256, 0, stream>>>(ugr, ugc, Arow, Acol, hs2);
  k_fused<<<1024, 512, 0, stream>>>(xbf, WsumBf, h1bf, g2wBf,
                                    hs2, WocatBf, g2b,
                                    rbo, rbs, cbo, cbs, outp);
}